// Round 1
// baseline (1777.415 us; speedup 1.0000x reference)
//
#include <hip/hip_runtime.h>

#define KDIM 256
#define NB 16384
#define NR 8192

// ---------------- norm kernel: inv[i] = 1 / max(||row||_2, eps) -------------
__global__ __launch_bounds__(256) void norm_kernel(const float* __restrict__ base,
                                                   const float* __restrict__ real,
                                                   float* __restrict__ inv) {
    int rid  = blockIdx.x * 4 + (threadIdx.x >> 6);
    int lane = threadIdx.x & 63;
    if (rid >= NB + NR) return;
    const float* src = (rid < NB) ? (base + (size_t)rid * KDIM)
                                  : (real + (size_t)(rid - NB) * KDIM);
    float4 v = *(const float4*)(src + lane * 4);
    float ss = v.x * v.x + v.y * v.y + v.z * v.z + v.w * v.w;
    #pragma unroll
    for (int off = 32; off > 0; off >>= 1) ss += __shfl_xor(ss, off);
    if (lane == 0) inv[rid] = 1.0f / fmaxf(sqrtf(ss), 1e-12f);
}

// ---------------- fused normalize-GEMM + running top-3 ----------------------
// block: 256 threads (16 tx x 16 ty), owns BM=64 rows of base.
// loops over N in BN=64 column tiles, K in chunks of 64.
// per-thread microtile: 4 rows (ty*4+i) x 4 cols (tx+16*j).
#define DOT(i, j, av, bv)                                                      \
    acc[i][j] = fmaf(av.x, bv.x, acc[i][j]);                                   \
    acc[i][j] = fmaf(av.y, bv.y, acc[i][j]);                                   \
    acc[i][j] = fmaf(av.z, bv.z, acc[i][j]);                                   \
    acc[i][j] = fmaf(av.w, bv.w, acc[i][j]);

__global__ __launch_bounds__(256) void simtopk_kernel(
    const float* __restrict__ A,   // base [NB][K]
    const float* __restrict__ B,   // real [NR][K]
    const float* __restrict__ invA,
    const float* __restrict__ invB,
    int* __restrict__ out) {
    __shared__ float sA[64 * 68];
    __shared__ float sB[64 * 68];

    const int tid = threadIdx.x;
    const int tx  = tid & 15;
    const int ty4 = (tid >> 4) << 2;
    const int m0  = blockIdx.x * 64;

    float t3v[4][3];
    int   t3i[4][3];
    #pragma unroll
    for (int i = 0; i < 4; ++i)
        #pragma unroll
        for (int s = 0; s < 3; ++s) { t3v[i][s] = -3.0e38f; t3i[i][s] = 0x7fffffff; }

    for (int n0 = 0; n0 < NR; n0 += 64) {
        float acc[4][4] = {{0.f}};
        for (int kc = 0; kc < KDIM; kc += 64) {
            __syncthreads();
            // stage A and B chunks, prescaled by inverse norms
            #pragma unroll
            for (int p = 0; p < 4; ++p) {
                int f   = tid + (p << 8);      // 0..1023 float4 slots
                int row = f >> 4;              // 16 float4 per row
                int c4  = (f & 15) << 2;
                float4 va = *(const float4*)(A + (size_t)(m0 + row) * KDIM + kc + c4);
                float  sa = invA[m0 + row];
                va.x *= sa; va.y *= sa; va.z *= sa; va.w *= sa;
                *(float4*)&sA[row * 68 + c4] = va;
                float4 vb = *(const float4*)(B + (size_t)(n0 + row) * KDIM + kc + c4);
                float  sb = invB[n0 + row];
                vb.x *= sb; vb.y *= sb; vb.z *= sb; vb.w *= sb;
                *(float4*)&sB[row * 68 + c4] = vb;
            }
            __syncthreads();
            #pragma unroll
            for (int k = 0; k < 64; k += 4) {
                float4 a0 = *(const float4*)&sA[(ty4 + 0) * 68 + k];
                float4 a1 = *(const float4*)&sA[(ty4 + 1) * 68 + k];
                float4 a2 = *(const float4*)&sA[(ty4 + 2) * 68 + k];
                float4 a3 = *(const float4*)&sA[(ty4 + 3) * 68 + k];
                float4 b0 = *(const float4*)&sB[(tx +  0) * 68 + k];
                float4 b1 = *(const float4*)&sB[(tx + 16) * 68 + k];
                float4 b2 = *(const float4*)&sB[(tx + 32) * 68 + k];
                float4 b3 = *(const float4*)&sB[(tx + 48) * 68 + k];
                DOT(0,0,a0,b0) DOT(0,1,a0,b1) DOT(0,2,a0,b2) DOT(0,3,a0,b3)
                DOT(1,0,a1,b0) DOT(1,1,a1,b1) DOT(1,2,a1,b2) DOT(1,3,a1,b3)
                DOT(2,0,a2,b0) DOT(2,1,a2,b1) DOT(2,2,a2,b2) DOT(2,3,a2,b3)
                DOT(3,0,a3,b0) DOT(3,1,a3,b1) DOT(3,2,a3,b2) DOT(3,3,a3,b3)
            }
        }
        // fold this column tile into the per-thread running top-3
        #pragma unroll
        for (int i = 0; i < 4; ++i) {
            #pragma unroll
            for (int j = 0; j < 4; ++j) {
                float v = acc[i][j];
                int   c = n0 + tx + 16 * j;
                bool b2 = (v > t3v[i][2]) | ((v == t3v[i][2]) & (c < t3i[i][2]));
                if (b2) {
                    bool b0 = (v > t3v[i][0]) | ((v == t3v[i][0]) & (c < t3i[i][0]));
                    bool b1 = (v > t3v[i][1]) | ((v == t3v[i][1]) & (c < t3i[i][1]));
                    if (b0) {
                        t3v[i][2]=t3v[i][1]; t3i[i][2]=t3i[i][1];
                        t3v[i][1]=t3v[i][0]; t3i[i][1]=t3i[i][0];
                        t3v[i][0]=v;         t3i[i][0]=c;
                    } else if (b1) {
                        t3v[i][2]=t3v[i][1]; t3i[i][2]=t3i[i][1];
                        t3v[i][1]=v;         t3i[i][1]=c;
                    } else {
                        t3v[i][2]=v;         t3i[i][2]=c;
                    }
                }
            }
        }
    }

    // merge top-3 across the 16 column-owning threads of each row, via LDS
    __syncthreads();
    float* mv = sA;
    int*   mi = (int*)sB;
    #pragma unroll
    for (int i = 0; i < 4; ++i) {
        int r = ty4 + i;
        #pragma unroll
        for (int s = 0; s < 3; ++s) {
            mv[r * 48 + tx * 3 + s] = t3v[i][s];
            mi[r * 48 + tx * 3 + s] = t3i[i][s];
        }
    }
    __syncthreads();
    if (tid < 64) {
        float v0 = -3.0e38f, v1 = -3.0e38f, v2 = -3.0e38f;
        int   i0 = 0x7fffffff, i1 = 0x7fffffff, i2 = 0x7fffffff;
        for (int e = 0; e < 48; ++e) {
            float v = mv[tid * 48 + e];
            int   c = mi[tid * 48 + e];
            bool b2 = (v > v2) | ((v == v2) & (c < i2));
            if (b2) {
                bool b0 = (v > v0) | ((v == v0) & (c < i0));
                bool b1 = (v > v1) | ((v == v1) & (c < i1));
                if (b0)      { v2=v1;i2=i1; v1=v0;i1=i0; v0=v;i0=c; }
                else if (b1) { v2=v1;i2=i1; v1=v;i1=c; }
                else         { v2=v;i2=c; }
            }
        }
        int r = m0 + tid;
        out[r * 3 + 0] = i0;
        out[r * 3 + 1] = i1;
        out[r * 3 + 2] = i2;
    }
}

extern "C" void kernel_launch(void* const* d_in, const int* in_sizes, int n_in,
                              void* d_out, int out_size, void* d_ws, size_t ws_size,
                              hipStream_t stream) {
    const float* base = (const float*)d_in[0];
    const float* real = (const float*)d_in[1];
    float* inv = (float*)d_ws;             // [NB + NR] inverse norms
    int*   out = (int*)d_out;

    hipLaunchKernelGGL(norm_kernel, dim3((NB + NR) / 4), dim3(256), 0, stream,
                       base, real, inv);
    hipLaunchKernelGGL(simtopk_kernel, dim3(NB / 64), dim3(256), 0, stream,
                       base, real, inv, inv + NB, out);
}